// Round 1
// baseline (229.720 us; speedup 1.0000x reference)
//
#include <hip/hip_runtime.h>

// WavUnPacking: x (8,256,128,128) f32 -> out (8,64,256,256) f32
// Channel quadrants (ll,lh,hl,hh), Haar inverse butterfly into 2x2 blocks.
//
// One thread handles 4 consecutive w positions (float4):
//   loads  : 4 x float4 (ll,lh,hl,hh)        = 64 B
//   stores : 2 x float4 to row 2h, 2 to 2h+1 = 64 B
// Fully coalesced; memory-bound kernel targeting HBM ceiling.

__global__ __launch_bounds__(256) void wav_unpack_kernel(
    const float* __restrict__ x, float* __restrict__ out) {
    constexpr int C4 = 64, H = 128, W = 128;
    constexpr int W4 = W / 4;               // 32 float4 groups per row
    constexpr int Q  = C4 * H * W;          // quadrant stride = 1,048,576 elems

    int t = blockIdx.x * blockDim.x + threadIdx.x;
    // t = ((b*64 + c)*128 + h)*32 + w4
    int w4 = t & (W4 - 1);
    int h  = (t >> 5) & (H - 1);
    int bc = t >> 12;                       // b*64 + c
    int b  = bc >> 6;

    // input channel index is b*256 + c = bc + b*192
    int in_base = ((bc + b * 192) * H + h) * W + (w4 << 2);

    const float4 ll = *(const float4*)(x + in_base);
    const float4 lh = *(const float4*)(x + in_base + Q);
    const float4 hl = *(const float4*)(x + in_base + 2 * Q);
    const float4 hh = *(const float4*)(x + in_base + 3 * Q);

    float4 e00, e01, e10, e11;
    e00.x = 0.5f * (ll.x + lh.x + hl.x + hh.x);
    e00.y = 0.5f * (ll.y + lh.y + hl.y + hh.y);
    e00.z = 0.5f * (ll.z + lh.z + hl.z + hh.z);
    e00.w = 0.5f * (ll.w + lh.w + hl.w + hh.w);

    e01.x = 0.5f * (ll.x + lh.x - hl.x - hh.x);
    e01.y = 0.5f * (ll.y + lh.y - hl.y - hh.y);
    e01.z = 0.5f * (ll.z + lh.z - hl.z - hh.z);
    e01.w = 0.5f * (ll.w + lh.w - hl.w - hh.w);

    e10.x = 0.5f * (ll.x - lh.x + hl.x - hh.x);
    e10.y = 0.5f * (ll.y - lh.y + hl.y - hh.y);
    e10.z = 0.5f * (ll.z - lh.z + hl.z - hh.z);
    e10.w = 0.5f * (ll.w - lh.w + hl.w - hh.w);

    e11.x = 0.5f * (ll.x - lh.x - hl.x + hh.x);
    e11.y = 0.5f * (ll.y - lh.y - hl.y + hh.y);
    e11.z = 0.5f * (ll.z - lh.z - hl.z + hh.z);
    e11.w = 0.5f * (ll.w - lh.w - hl.w + hh.w);

    // out[b, c, 2h + r, 8*w4 + ...]; row stride 256, chan stride 256*256
    int out_base = (bc * 256 + 2 * h) * 256 + (w4 << 3);

    float4 r0a = { e00.x, e01.x, e00.y, e01.y };
    float4 r0b = { e00.z, e01.z, e00.w, e01.w };
    float4 r1a = { e10.x, e11.x, e10.y, e11.y };
    float4 r1b = { e10.z, e11.z, e10.w, e11.w };

    *(float4*)(out + out_base)           = r0a;
    *(float4*)(out + out_base + 4)       = r0b;
    *(float4*)(out + out_base + 256)     = r1a;
    *(float4*)(out + out_base + 256 + 4) = r1b;
}

extern "C" void kernel_launch(void* const* d_in, const int* in_sizes, int n_in,
                              void* d_out, int out_size, void* d_ws, size_t ws_size,
                              hipStream_t stream) {
    const float* x = (const float*)d_in[0];
    float* out = (float*)d_out;
    // total threads = 8 * 64 * 128 * 32 = 2,097,152
    constexpr int total = 8 * 64 * 128 * 32;
    constexpr int block = 256;
    wav_unpack_kernel<<<total / block, block, 0, stream>>>(x, out);
}

// Round 2
// 220.454 us; speedup vs baseline: 1.0420x; 1.0420x over previous
//
#include <hip/hip_runtime.h>

// WavUnPacking: x (8,256,128,128) f32 -> out (8,64,256,256) f32
// Channel quadrants (ll,lh,hl,hh), Haar inverse butterfly into 2x2 blocks.
//
// R1 layout: one thread = 2 consecutive input w positions.
//   loads : 4 x float2 (ll,lh,hl,hh), 8 B/lane  -> 512 B contiguous per wave instr
//   stores: 2 x float4 (row 2h, row 2h+1), 16 B/lane -> 1 KB contiguous per wave instr
// Every VMEM instruction is a dense contiguous wave transaction (the R0 version
// had 50%-dense strided store instructions). Nontemporal on both sides: pure
// streaming, no reuse.

typedef float v2f __attribute__((ext_vector_type(2)));
typedef float v4f __attribute__((ext_vector_type(4)));

__global__ __launch_bounds__(256) void wav_unpack_kernel(
    const float* __restrict__ x, float* __restrict__ out) {
    constexpr int H = 128, W = 128;
    constexpr int W2 = W / 2;               // 64 float2 groups per input row
    constexpr int Q  = 64 * H * W;          // quadrant stride = 1,048,576 elems

    int t = blockIdx.x * blockDim.x + threadIdx.x;
    // t = ((b*64 + c)*128 + h)*64 + w2
    int w2 = t & (W2 - 1);
    int h  = (t >> 6) & (H - 1);
    int bc = t >> 13;                       // b*64 + c
    int b  = bc >> 6;

    // input channel index is b*256 + c = bc + b*192
    int in_base = ((bc + b * 192) * H + h) * W + (w2 << 1);

    const v2f ll = __builtin_nontemporal_load((const v2f*)(x + in_base));
    const v2f lh = __builtin_nontemporal_load((const v2f*)(x + in_base + Q));
    const v2f hl = __builtin_nontemporal_load((const v2f*)(x + in_base + 2 * Q));
    const v2f hh = __builtin_nontemporal_load((const v2f*)(x + in_base + 3 * Q));

    v4f r0, r1;
    // row 2h:   e00, e01 interleaved for the two w positions
    r0.x = 0.5f * (ll.x + lh.x + hl.x + hh.x);
    r0.y = 0.5f * (ll.x + lh.x - hl.x - hh.x);
    r0.z = 0.5f * (ll.y + lh.y + hl.y + hh.y);
    r0.w = 0.5f * (ll.y + lh.y - hl.y - hh.y);
    // row 2h+1: e10, e11 interleaved
    r1.x = 0.5f * (ll.x - lh.x + hl.x - hh.x);
    r1.y = 0.5f * (ll.x - lh.x - hl.x + hh.x);
    r1.z = 0.5f * (ll.y - lh.y + hl.y - hh.y);
    r1.w = 0.5f * (ll.y - lh.y - hl.y + hh.y);

    // out[b, c, 2h + r, 4*w2 + ...]; row stride 256, chan stride 256*256
    int out_base = (bc * 256 + 2 * h) * 256 + (w2 << 2);

    __builtin_nontemporal_store(r0, (v4f*)(out + out_base));
    __builtin_nontemporal_store(r1, (v4f*)(out + out_base + 256));
}

extern "C" void kernel_launch(void* const* d_in, const int* in_sizes, int n_in,
                              void* d_out, int out_size, void* d_ws, size_t ws_size,
                              hipStream_t stream) {
    const float* x = (const float*)d_in[0];
    float* out = (float*)d_out;
    // total threads = 8 * 64 * 128 * 64 = 4,194,304
    constexpr int total = 8 * 64 * 128 * 64;
    constexpr int block = 256;
    wav_unpack_kernel<<<total / block, block, 0, stream>>>(x, out);
}